// Round 1
// baseline (126.897 us; speedup 1.0000x reference)
//
#include <hip/hip_runtime.h>
#include <math.h>

// Problem constants (from reference): bs=8, n=32, dy=64, dc=256, M=8, nm=256.
// out[b, i*8+a, j*8+c, ch] = (W[ch,:]·E[b,i,j,:] + W[ch,:]·pe[a*8+c,:])
//                            * e_mask1[b,i] * e_mask2[b, (j*8+c)%32]
// Linearity lets us precompute Cpe = W·pe (64x256) and per-(b,i,j) ce = W·E.

// Kernel 1: Cpe[pos, ch] = sum_d W[ch,d] * pe[pos,d], pos in [0,64), ch in [0,256)
__global__ __launch_bounds__(256) void cpe_kernel(const float* __restrict__ W,
                                                  float* __restrict__ Cpe) {
    const int pos = blockIdx.x;      // 0..63
    const int t   = threadIdx.x;     // 0..255 (= channel)
    __shared__ float peL[64];
    if (t < 64) {
        // d = t ; k2 = 2*floor(d/2); div = exp(-k2 * ln(10000)/64)
        const float k2  = (float)(t & ~1);
        const float div = expf(-k2 * (logf(10000.0f) / 64.0f));
        const float arg = (float)pos * div;
        peL[t] = (t & 1) ? cosf(arg) : sinf(arg);
    }
    __syncthreads();
    const float4* W4 = (const float4*)W;  // W row ch = 16 float4
    float acc = 0.0f;
#pragma unroll
    for (int d4 = 0; d4 < 16; ++d4) {
        float4 w = W4[t * 16 + d4];
        acc += w.x * peL[4 * d4 + 0] + w.y * peL[4 * d4 + 1] +
               w.z * peL[4 * d4 + 2] + w.w * peL[4 * d4 + 3];
    }
    Cpe[pos * 256 + t] = acc;
}

// Kernel 2: one block per (b,i,j). 256 threads, 4 waves.
//  Phase A: load E[b,i,j,0:64] + m2 slice into LDS.
//  Phase B: thread t computes ce[t] = W[t,:]·Ev -> LDS.
//  Phase C: wave w handles positions p = w*16 .. w*16+15 (p = a*8+c);
//           lane g owns channels 4g..4g+3; float4 store per position.
__global__ __launch_bounds__(256) void etoc_kernel(const float* __restrict__ E,
                                                   const float* __restrict__ m1p,
                                                   const float* __restrict__ m2p,
                                                   const float* __restrict__ W,
                                                   const float* __restrict__ Cpe,
                                                   float* __restrict__ out) {
    const int blk = blockIdx.x;          // b*1024 + i*32 + j
    const int j = blk & 31;
    const int i = (blk >> 5) & 31;
    const int b = blk >> 10;
    const int t = threadIdx.x;

    __shared__ float Ev[64];
    __shared__ float ceS[256];
    __shared__ float m2s[8];

    if (t < 64) {
        Ev[t] = E[((size_t)((b * 32 + i) * 32 + j) << 6) + t];
    }
    if (t >= 64 && t < 72) {
        // jj % 32 == (j%4)*8 + c
        m2s[t - 64] = m2p[b * 32 + ((j & 3) << 3) + (t - 64)];
    }
    __syncthreads();

    // Phase B: ce[t] = W[t,:]·Ev (Ev reads are LDS broadcasts)
    {
        const float4* W4 = (const float4*)W;
        float acc = 0.0f;
#pragma unroll
        for (int d4 = 0; d4 < 16; ++d4) {
            float4 w = W4[t * 16 + d4];
            acc += w.x * Ev[4 * d4 + 0] + w.y * Ev[4 * d4 + 1] +
                   w.z * Ev[4 * d4 + 2] + w.w * Ev[4 * d4 + 3];
        }
        ceS[t] = acc;
    }
    __syncthreads();

    const float m1 = m1p[b * 32 + i];
    const int w = t >> 6;        // wave 0..3
    const int g = t & 63;        // lane group: channels 4g..4g+3

    const float4 ce4 = ((const float4*)ceS)[g];
    const float4* Cpe4 = (const float4*)Cpe;
    float4* out4 = (float4*)out;

    // out float4 index = ((b*256 + ii)*256 + jj)*64 + g
    const size_t rowBase = (((size_t)b * 256 + (size_t)i * 8) * 256 + (size_t)j * 8);

#pragma unroll
    for (int p0 = 0; p0 < 16; ++p0) {
        const int p = w * 16 + p0;   // position = a*8 + c
        const int a = p >> 3;
        const int c = p & 7;
        const float m = m1 * m2s[c];
        const float4 q = Cpe4[p * 64 + g];
        float4 r;
        r.x = (ce4.x + q.x) * m;
        r.y = (ce4.y + q.y) * m;
        r.z = (ce4.z + q.z) * m;
        r.w = (ce4.w + q.w) * m;
        const size_t idx = (rowBase + (size_t)a * 256 + (size_t)c) * 64 + (size_t)g;
        out4[idx] = r;
    }
}

extern "C" void kernel_launch(void* const* d_in, const int* in_sizes, int n_in,
                              void* d_out, int out_size, void* d_ws, size_t ws_size,
                              hipStream_t stream) {
    const float* E   = (const float*)d_in[0];   // (8,32,32,64)
    const float* m1p = (const float*)d_in[1];   // (8,32,1,1)
    const float* m2p = (const float*)d_in[2];   // (8,1,32,1)
    const float* W   = (const float*)d_in[3];   // (256,64)
    float* out = (float*)d_out;                 // (8,256,256,256)
    float* Cpe = (float*)d_ws;                  // 64*256 floats = 64 KB

    cpe_kernel<<<64, 256, 0, stream>>>(W, Cpe);
    etoc_kernel<<<8192, 256, 0, stream>>>(E, m1p, m2p, W, Cpe, out);
}

// Round 3
// 114.296 us; speedup vs baseline: 1.1103x; 1.1103x over previous
//
#include <hip/hip_runtime.h>
#include <math.h>

typedef float f32x4 __attribute__((ext_vector_type(4)));

// Problem constants: bs=8, n=32, dy=64, dc=256, M=8, nm=256.
// out[b, i*8+a, (jg*4+dj)*8+c, ch] =
//    (W[ch,:]·E[b,i,jg*4+dj,:] + Cpe[a*8+c, ch]) * m1[b,i] * m2[b, dj*8+c]
// where Cpe = W·pe (precomputed, 64x256 = 64 KB in d_ws).

// Kernel 1: Cpe[pos, ch] = sum_d W[ch,d] * pe[pos,d]
__global__ __launch_bounds__(256) void cpe_kernel(const float* __restrict__ W,
                                                  float* __restrict__ Cpe) {
    const int pos = blockIdx.x;      // 0..63
    const int t   = threadIdx.x;     // 0..255 (= channel)
    __shared__ float peL[64];
    if (t < 64) {
        const float k2  = (float)(t & ~1);
        const float div = expf(-k2 * (logf(10000.0f) / 64.0f));
        const float arg = (float)pos * div;
        peL[t] = (t & 1) ? cosf(arg) : sinf(arg);
    }
    __syncthreads();
    const f32x4* W4 = (const f32x4*)W;
    float acc = 0.0f;
#pragma unroll
    for (int d4 = 0; d4 < 16; ++d4) {
        f32x4 w = W4[t * 16 + d4];
        acc += w.x * peL[4 * d4 + 0] + w.y * peL[4 * d4 + 1] +
               w.z * peL[4 * d4 + 2] + w.w * peL[4 * d4 + 3];
    }
    Cpe[pos * 256 + t] = acc;
}

// Kernel 2: one block per (b, i, jg) with jg covering 4 consecutive j.
// 256 threads / 4 waves. Wave w owns positions p = w*16..w*16+15 (p = a*8+c),
// lane g owns channels 4g..4g+3. Each Cpe float4 is loaded once and reused
// across the 4 j's in registers.
__global__ __launch_bounds__(256) void etoc_kernel(const float* __restrict__ E,
                                                   const float* __restrict__ m1p,
                                                   const float* __restrict__ m2p,
                                                   const float* __restrict__ W,
                                                   const float* __restrict__ Cpe,
                                                   float* __restrict__ out) {
    const int blk = blockIdx.x;          // b*256 + i*8 + jg
    const int jg = blk & 7;
    const int i  = (blk >> 3) & 31;
    const int b  = blk >> 8;
    const int t  = threadIdx.x;

    __shared__ float Ev[4 * 64];    // E rows for the 4 j's
    __shared__ float ceS[4 * 256];  // ce[dj][ch]
    __shared__ float m2s[32];       // m2 slice for this b

    // Phase A: 256 threads load 4 rows x 64 floats (1 KB, coalesced)
    Ev[t] = E[((size_t)((b * 32 + i) * 32 + jg * 4) << 6) + t];
    if (t < 32) m2s[t] = m2p[b * 32 + t];
    __syncthreads();

    // Phase B: thread t = channel; load W row once, reuse for 4 dj.
    {
        const f32x4* W4 = (const f32x4*)W;
        f32x4 wr[16];
#pragma unroll
        for (int d4 = 0; d4 < 16; ++d4) wr[d4] = W4[t * 16 + d4];
#pragma unroll
        for (int dj = 0; dj < 4; ++dj) {
            const float* e = &Ev[dj * 64];
            float acc = 0.0f;
#pragma unroll
            for (int d4 = 0; d4 < 16; ++d4) {
                acc += wr[d4].x * e[4 * d4 + 0] + wr[d4].y * e[4 * d4 + 1] +
                       wr[d4].z * e[4 * d4 + 2] + wr[d4].w * e[4 * d4 + 3];
            }
            ceS[dj * 256 + t] = acc;
        }
    }
    __syncthreads();

    const float m1v = m1p[b * 32 + i];
    const int w = t >> 6;        // wave 0..3 -> position quarter
    const int g = t & 63;        // channel group: channels 4g..4g+3

    f32x4 ce4[4];
#pragma unroll
    for (int dj = 0; dj < 4; ++dj) ce4[dj] = ((const f32x4*)(ceS + dj * 256))[g];

    const f32x4* Cpe4 = (const f32x4*)Cpe;
    f32x4* out4 = (f32x4*)out;

    // float4 index: ((b*256 + i*8 + a)*256 + jg*32 + dj*8 + c)*64 + g
    const size_t base = (((size_t)(b * 256 + i * 8) * 256) + (size_t)jg * 32) * 64 + (size_t)g;

#pragma unroll
    for (int p0 = 0; p0 < 16; ++p0) {
        const int p = w * 16 + p0;   // position = a*8 + c
        const int a = p >> 3;
        const int c = p & 7;
        const f32x4 q = Cpe4[p * 64 + g];
        const size_t idxA = base + (size_t)a * 16384 + (size_t)c * 64;
#pragma unroll
        for (int dj = 0; dj < 4; ++dj) {
            const float m = m1v * m2s[dj * 8 + c];
            f32x4 r = (ce4[dj] + q) * m;
            __builtin_nontemporal_store(r, &out4[idxA + (size_t)dj * 512]);
        }
    }
}

extern "C" void kernel_launch(void* const* d_in, const int* in_sizes, int n_in,
                              void* d_out, int out_size, void* d_ws, size_t ws_size,
                              hipStream_t stream) {
    const float* E   = (const float*)d_in[0];   // (8,32,32,64)
    const float* m1p = (const float*)d_in[1];   // (8,32,1,1)
    const float* m2p = (const float*)d_in[2];   // (8,1,32,1)
    const float* W   = (const float*)d_in[3];   // (256,64)
    float* out = (float*)d_out;                 // (8,256,256,256)
    float* Cpe = (float*)d_ws;                  // 64*256 floats = 64 KB

    cpe_kernel<<<64, 256, 0, stream>>>(W, Cpe);
    etoc_kernel<<<2048, 256, 0, stream>>>(E, m1p, m2p, W, Cpe, out);
}